// Round 3
// baseline (486.798 us; speedup 1.0000x reference)
//
#include <hip/hip_runtime.h>

#define BATCH 512
#define SEQ   256
#define CEMB  384
#define HD    64
#define MROWS (BATCH*SEQ)

typedef __bf16 bf16_t;
typedef __bf16 bf16x4 __attribute__((ext_vector_type(4)));
typedef __bf16 bf16x8 __attribute__((ext_vector_type(8)));
typedef float  f32x4  __attribute__((ext_vector_type(4)));

#define GLOAD_LDS16(gp, lp) \
    __builtin_amdgcn_global_load_lds((const __attribute__((address_space(1))) void*)(gp), \
                                     (__attribute__((address_space(3))) void*)(lp), 16, 0, 0)

// ---------- kernel 1: gather W into MFMA-fragment-major bf16 array Wf ----------
// Wf element idx = (f*64 + lane)*8 + j ; f = s*12 + ni (s=K-step 0..11, ni=N-tile 0..11)
// value = W_m[k][d] with n = ni*16 + (lane&15), k = s*32 + (lane>>4)*8 + j, m = n/64, d = n%64
__global__ void wconv_kernel(const float* __restrict__ Wq, const float* __restrict__ Wk,
                             const float* __restrict__ Wv, bf16_t* __restrict__ Wf) {
    int idx = blockIdx.x * 256 + threadIdx.x;
    if (idx >= 144 * 512) return;
    int j = idx & 7, lane = (idx >> 3) & 63, f = idx >> 9;
    int ni = f % 12, s = f / 12;
    int n = ni * 16 + (lane & 15);
    int k = s * 32 + ((lane >> 4) << 3) + j;
    const float* W = (n < 64) ? Wq : ((n < 128) ? Wk : Wv);
    Wf[idx] = (bf16_t)W[k * HD + (n & 63)];
}

// ---------- kernel 2: qkv projection, W resident in LDS, barrier-free main loop ----------
// 256 blocks (1/CU), 1024 threads (16 waves, 4/SIMD). Block owns 512 rows; each wave
// does 2 independent 16-row stripes. A straight from global (2-slab prefetch), B from LDS.
__global__ __launch_bounds__(1024, 4)
void qkv_kernel(const float* __restrict__ x, const bf16_t* __restrict__ Wf,
                bf16_t* __restrict__ qg, bf16_t* __restrict__ kg, bf16_t* __restrict__ vg) {
    __shared__ char smem[147456];                 // full W, fragment-major

    const int tid = threadIdx.x;
    const int w = tid >> 6, lane = tid & 63;
    const int l15 = lane & 15, l4 = lane >> 4;

    // stage entire Wf linearly: 1024 threads x 9 x 16B = 147456 B
    #pragma unroll
    for (int i = 0; i < 9; ++i)
        GLOAD_LDS16((const char*)Wf + tid * 16 + i * 16384, smem + tid * 16 + i * 16384);
    __syncthreads();

    const long blockbase = (long)blockIdx.x * 512;

    for (int it = 0; it < 2; ++it) {
        const long rowbase = blockbase + (it * 16 + w) * 16;   // stripe base
        const long arow = rowbase + l15;
        const float* aptr = x + arow * CEMB + l4 * 8;

        f32x4 acc[12];
        #pragma unroll
        for (int ni = 0; ni < 12; ++ni) acc[ni] = f32x4{0.f, 0.f, 0.f, 0.f};

        // rotating 3-slot prefetch, all indices compile-time (full unroll)
        float4 raw[3][2];
        #pragma unroll
        for (int pp = 0; pp < 2; ++pp) {
            raw[pp][0] = *(const float4*)(aptr + pp * 32);
            raw[pp][1] = *(const float4*)(aptr + pp * 32 + 4);
        }

        #pragma unroll
        for (int ks = 0; ks < 12; ++ks) {
            const int cur = ks % 3, nxt = (ks + 2) % 3;
            if (ks < 10) {
                raw[nxt][0] = *(const float4*)(aptr + (ks + 2) * 32);
                raw[nxt][1] = *(const float4*)(aptr + (ks + 2) * 32 + 4);
            }
            bf16x8 af;
            af[0] = (bf16_t)raw[cur][0].x; af[1] = (bf16_t)raw[cur][0].y;
            af[2] = (bf16_t)raw[cur][0].z; af[3] = (bf16_t)raw[cur][0].w;
            af[4] = (bf16_t)raw[cur][1].x; af[5] = (bf16_t)raw[cur][1].y;
            af[6] = (bf16_t)raw[cur][1].z; af[7] = (bf16_t)raw[cur][1].w;
            #pragma unroll
            for (int ni = 0; ni < 12; ++ni) {
                bf16x8 bf = *(const bf16x8*)(smem + (ks * 12 + ni) * 1024 + lane * 16);
                acc[ni] = __builtin_amdgcn_mfma_f32_16x16x32_bf16(af, bf, acc[ni], 0, 0, 0);
            }
        }

        #pragma unroll
        for (int ni = 0; ni < 12; ++ni) {
            int col = ni * 16 + l15;
            bf16_t* dst = (col < 64) ? qg : ((col < 128) ? kg : vg);
            int d = col & 63;
            #pragma unroll
            for (int r = 0; r < 4; ++r) {
                long rg = rowbase + l4 * 4 + r;
                dst[rg * HD + d] = (bf16_t)acc[ni][r];
            }
        }
    }
}

// ---------- kernel 3: causal flash attention, one block per batch (unchanged) ----------
__global__ __launch_bounds__(256, 2)
void attn_kernel(const bf16_t* __restrict__ qg, const bf16_t* __restrict__ kg,
                 const bf16_t* __restrict__ vg, float* __restrict__ out) {
    __shared__ char smem[81920];
    // [0,32768):     K  [256][64] bf16, swizzle ^((s&7)<<4)
    // [32768,65536): Vt [64][256] bf16, swizzle ^((d&7)<<4)
    // [65536,81920): P  per-wave [64][32] bf16, swizzle ^((q&3)<<4)

    const int tid = threadIdx.x;
    const int w = tid >> 6, lane = tid & 63;
    const int l15 = lane & 15, l4 = lane >> 4;
    const long base = (long)blockIdx.x * SEQ * HD;

    for (int it = 0; it < 8; ++it) {
        int i = tid + it * 256;
        int s = i >> 3, cb = (i & 7) * 16;
        bf16x8 kv = *(const bf16x8*)(kg + base + (long)i * 8);
        *(bf16x8*)(smem + s * 128 + (cb ^ ((s & 7) << 4))) = kv;
    }
    for (int it = 0; it < 8; ++it) {
        int i = tid + it * 256;
        int s = i >> 3, d0 = (i & 7) * 8;
        bf16x8 vv = *(const bf16x8*)(vg + base + (long)i * 8);
        #pragma unroll
        for (int j = 0; j < 8; ++j) {
            int d = d0 + j;
            *(bf16_t*)(smem + 32768 + d * 512 + ((s * 2) ^ ((d & 7) << 4))) = vv[j];
        }
    }

    bf16x8 qf[4][2];
    #pragma unroll
    for (int mi = 0; mi < 4; ++mi) {
        int row = mi * 64 + w * 16 + l15;
        #pragma unroll
        for (int kk = 0; kk < 2; ++kk)
            qf[mi][kk] = *(const bf16x8*)(qg + base + (long)row * HD + kk * 32 + l4 * 8);
    }

    __syncthreads();

    f32x4 oacc[4][4];
    float mrow[4][4], lrow[4][4];
    #pragma unroll
    for (int mi = 0; mi < 4; ++mi) {
        #pragma unroll
        for (int di = 0; di < 4; ++di) oacc[mi][di] = f32x4{0.f, 0.f, 0.f, 0.f};
        #pragma unroll
        for (int r = 0; r < 4; ++r) { mrow[mi][r] = -1e30f; lrow[mi][r] = 0.f; }
    }

    char* Pw = smem + 65536 + w * 4096;
    const int ntiles = (w < 2) ? 7 : 8;
    const float LOG2E = 1.44269504089f;

    for (int st = 0; st < ntiles; ++st) {
        f32x4 sacc[4][2];
        #pragma unroll
        for (int mi = 0; mi < 4; ++mi)
            #pragma unroll
            for (int ni = 0; ni < 2; ++ni) sacc[mi][ni] = f32x4{0.f, 0.f, 0.f, 0.f};

        #pragma unroll
        for (int kk = 0; kk < 2; ++kk) {
            #pragma unroll
            for (int ni = 0; ni < 2; ++ni) {
                int s = st * 32 + ni * 16 + l15;
                bf16x8 kf = *(const bf16x8*)(smem + s * 128 + (((kk * 32 + l4 * 8) * 2) ^ ((s & 7) << 4)));
                #pragma unroll
                for (int mi = 0; mi < 4; ++mi) {
                    if (st * 32 <= mi * 64 + w * 16 + 15)
                        sacc[mi][ni] = __builtin_amdgcn_mfma_f32_16x16x32_bf16(qf[mi][kk], kf, sacc[mi][ni], 0, 0, 0);
                }
            }
        }

        #pragma unroll
        for (int mi = 0; mi < 4; ++mi) {
            const int R = mi * 64 + w * 16;
            if (st * 32 > R + 15) continue;
            const bool needmask = (st * 32 + 31 > R);
            #pragma unroll
            for (int r = 0; r < 4; ++r) {
                float s0 = sacc[mi][0][r] * 0.125f;
                float s1 = sacc[mi][1][r] * 0.125f;
                if (needmask) {
                    int row = R + l4 * 4 + r;
                    if (st * 32 + l15 > row)      s0 = -1e30f;
                    if (st * 32 + 16 + l15 > row) s1 = -1e30f;
                }
                float mx = fmaxf(s0, s1);
                mx = fmaxf(mx, __shfl_xor(mx, 1));
                mx = fmaxf(mx, __shfl_xor(mx, 2));
                mx = fmaxf(mx, __shfl_xor(mx, 4));
                mx = fmaxf(mx, __shfl_xor(mx, 8));
                float mold = mrow[mi][r];
                float mnew = fmaxf(mold, mx);
                float alpha = exp2f((mold - mnew) * LOG2E);
                float p0 = exp2f((s0 - mnew) * LOG2E);
                float p1 = exp2f((s1 - mnew) * LOG2E);
                mrow[mi][r] = mnew;
                float rs = p0 + p1;
                rs += __shfl_xor(rs, 1);
                rs += __shfl_xor(rs, 2);
                rs += __shfl_xor(rs, 4);
                rs += __shfl_xor(rs, 8);
                lrow[mi][r] = lrow[mi][r] * alpha + rs;
                #pragma unroll
                for (int di = 0; di < 4; ++di) oacc[mi][di][r] *= alpha;
                int q = mi * 16 + l4 * 4 + r;
                *(bf16_t*)(Pw + q * 64 + ((l15 * 2) ^ ((q & 3) << 4))) = (bf16_t)p0;
                *(bf16_t*)(Pw + q * 64 + ((32 + l15 * 2) ^ ((q & 3) << 4))) = (bf16_t)p1;
            }
        }

        #pragma unroll
        for (int mi = 0; mi < 4; ++mi) {
            if (st * 32 > mi * 64 + w * 16 + 15) continue;
            int q = mi * 16 + l15;
            bf16x8 pf = *(const bf16x8*)(Pw + q * 64 + ((l4 * 16) ^ ((q & 3) << 4)));
            #pragma unroll
            for (int di = 0; di < 4; ++di) {
                int d = di * 16 + l15;
                bf16x8 vf = *(const bf16x8*)(smem + 32768 + d * 512 + (((st * 32 + l4 * 8) * 2) ^ ((d & 7) << 4)));
                oacc[mi][di] = __builtin_amdgcn_mfma_f32_16x16x32_bf16(pf, vf, oacc[mi][di], 0, 0, 0);
            }
        }
    }

    #pragma unroll
    for (int mi = 0; mi < 4; ++mi) {
        #pragma unroll
        for (int r = 0; r < 4; ++r) {
            float inv = 1.f / lrow[mi][r];
            long row = mi * 64 + w * 16 + l4 * 4 + r;
            #pragma unroll
            for (int di = 0; di < 4; ++di)
                out[base + row * HD + di * 16 + l15] = oacc[mi][di][r] * inv;
        }
    }
}

extern "C" void kernel_launch(void* const* d_in, const int* in_sizes, int n_in,
                              void* d_out, int out_size, void* d_ws, size_t ws_size,
                              hipStream_t stream) {
    const float* x  = (const float*)d_in[0];
    const float* Wq = (const float*)d_in[1];
    const float* Wk = (const float*)d_in[2];
    const float* Wv = (const float*)d_in[3];
    float* out = (float*)d_out;

    bf16_t* Wf = (bf16_t*)d_ws;                       // 147,456 B fragment-major W
    bf16_t* qg = (bf16_t*)((char*)d_ws + (1 << 20));
    bf16_t* kg = qg + (long)MROWS * HD;
    bf16_t* vg = kg + (long)MROWS * HD;

    wconv_kernel<<<dim3(288), dim3(256), 0, stream>>>(Wq, Wk, Wv, Wf);
    qkv_kernel<<<dim3(256), dim3(1024), 0, stream>>>(x, Wf, qg, kg, vg);
    attn_kernel<<<dim3(BATCH), dim3(256), 0, stream>>>(qg, kg, vg, out);
}

// Round 4
// 345.424 us; speedup vs baseline: 1.4093x; 1.4093x over previous
//
#include <hip/hip_runtime.h>

#define BATCH 512
#define SEQ   256
#define CEMB  384
#define HD    64
#define MROWS (BATCH*SEQ)

typedef __bf16 bf16_t;
typedef __bf16 bf16x4 __attribute__((ext_vector_type(4)));
typedef __bf16 bf16x8 __attribute__((ext_vector_type(8)));
typedef float  f32x4  __attribute__((ext_vector_type(4)));

#define GLOAD_LDS16(gp, lp) \
    __builtin_amdgcn_global_load_lds((const __attribute__((address_space(1))) void*)(gp), \
                                     (__attribute__((address_space(3))) void*)(lp), 16, 0, 0)

// ---------- kernel 1: gather W into MFMA-fragment-major bf16 array Wf ----------
// Wf element idx = (f*64 + lane)*8 + j ; f = s*12 + ni (s=K-step 0..11, ni=N-tile 0..11)
// value = W_m[k][d] with n = ni*16 + (lane&15), k = s*32 + (lane>>4)*8 + j, m = n/64, d = n%64
__global__ void wconv_kernel(const float* __restrict__ Wq, const float* __restrict__ Wk,
                             const float* __restrict__ Wv, bf16_t* __restrict__ Wf) {
    int idx = blockIdx.x * 256 + threadIdx.x;
    if (idx >= 144 * 512) return;
    int j = idx & 7, lane = (idx >> 3) & 63, f = idx >> 9;
    int ni = f % 12, s = f / 12;
    int n = ni * 16 + (lane & 15);
    int k = s * 32 + ((lane >> 4) << 3) + j;
    const float* W = (n < 64) ? Wq : ((n < 128) ? Wk : Wv);
    Wf[idx] = (bf16_t)W[k * HD + (n & 63)];
}

// ---------- kernel 2: qkv projection, W resident in LDS, barrier-free main loop ----------
// 256 blocks (1/CU), 512 threads (8 waves = 2/SIMD; 144KB LDS forces 1 block/CU anyway).
// waves_per_eu(2,2) pins the allocator target -> 256 VGPR budget, no spill.
__global__ __attribute__((amdgpu_flat_work_group_size(512, 512), amdgpu_waves_per_eu(2, 2)))
void qkv_kernel(const float* __restrict__ x, const bf16_t* __restrict__ Wf,
                bf16_t* __restrict__ qg, bf16_t* __restrict__ kg, bf16_t* __restrict__ vg) {
    __shared__ char smem[147456];                 // full W, fragment-major

    const int tid = threadIdx.x;
    const int w = tid >> 6, lane = tid & 63;
    const int l15 = lane & 15, l4 = lane >> 4;

    // stage entire Wf linearly: 512 threads x 18 x 16B = 147456 B
    #pragma unroll
    for (int i = 0; i < 18; ++i)
        GLOAD_LDS16((const char*)Wf + tid * 16 + i * 8192, smem + tid * 16 + i * 8192);
    __syncthreads();

    const long blockbase = (long)blockIdx.x * 512;

    for (int it = 0; it < 4; ++it) {
        const long rowbase = blockbase + (it * 8 + w) * 16;    // stripe base
        const long arow = rowbase + l15;
        const float* aptr = x + arow * CEMB + l4 * 8;

        f32x4 acc[12];
        #pragma unroll
        for (int ni = 0; ni < 12; ++ni) acc[ni] = f32x4{0.f, 0.f, 0.f, 0.f};

        // rotating 3-slot prefetch, all indices compile-time (full unroll)
        float4 raw[3][2];
        #pragma unroll
        for (int pp = 0; pp < 2; ++pp) {
            raw[pp][0] = *(const float4*)(aptr + pp * 32);
            raw[pp][1] = *(const float4*)(aptr + pp * 32 + 4);
        }

        #pragma unroll
        for (int ks = 0; ks < 12; ++ks) {
            const int cur = ks % 3, nxt = (ks + 2) % 3;
            if (ks < 10) {
                raw[nxt][0] = *(const float4*)(aptr + (ks + 2) * 32);
                raw[nxt][1] = *(const float4*)(aptr + (ks + 2) * 32 + 4);
            }
            bf16x8 af;
            af[0] = (bf16_t)raw[cur][0].x; af[1] = (bf16_t)raw[cur][0].y;
            af[2] = (bf16_t)raw[cur][0].z; af[3] = (bf16_t)raw[cur][0].w;
            af[4] = (bf16_t)raw[cur][1].x; af[5] = (bf16_t)raw[cur][1].y;
            af[6] = (bf16_t)raw[cur][1].z; af[7] = (bf16_t)raw[cur][1].w;
            #pragma unroll
            for (int ni = 0; ni < 12; ++ni) {
                bf16x8 bf = *(const bf16x8*)(smem + (ks * 12 + ni) * 1024 + lane * 16);
                acc[ni] = __builtin_amdgcn_mfma_f32_16x16x32_bf16(af, bf, acc[ni], 0, 0, 0);
            }
        }

        #pragma unroll
        for (int ni = 0; ni < 12; ++ni) {
            int col = ni * 16 + l15;
            bf16_t* dst = (col < 64) ? qg : ((col < 128) ? kg : vg);
            int d = col & 63;
            #pragma unroll
            for (int r = 0; r < 4; ++r) {
                long rg = rowbase + l4 * 4 + r;
                dst[rg * HD + d] = (bf16_t)acc[ni][r];
            }
        }
    }
}

// ---------- kernel 3: causal flash attention, one block per batch (unchanged) ----------
__global__ __launch_bounds__(256, 2)
void attn_kernel(const bf16_t* __restrict__ qg, const bf16_t* __restrict__ kg,
                 const bf16_t* __restrict__ vg, float* __restrict__ out) {
    __shared__ char smem[81920];
    // [0,32768):     K  [256][64] bf16, swizzle ^((s&7)<<4)
    // [32768,65536): Vt [64][256] bf16, swizzle ^((d&7)<<4)
    // [65536,81920): P  per-wave [64][32] bf16, swizzle ^((q&3)<<4)

    const int tid = threadIdx.x;
    const int w = tid >> 6, lane = tid & 63;
    const int l15 = lane & 15, l4 = lane >> 4;
    const long base = (long)blockIdx.x * SEQ * HD;

    for (int it = 0; it < 8; ++it) {
        int i = tid + it * 256;
        int s = i >> 3, cb = (i & 7) * 16;
        bf16x8 kv = *(const bf16x8*)(kg + base + (long)i * 8);
        *(bf16x8*)(smem + s * 128 + (cb ^ ((s & 7) << 4))) = kv;
    }
    for (int it = 0; it < 8; ++it) {
        int i = tid + it * 256;
        int s = i >> 3, d0 = (i & 7) * 8;
        bf16x8 vv = *(const bf16x8*)(vg + base + (long)i * 8);
        #pragma unroll
        for (int j = 0; j < 8; ++j) {
            int d = d0 + j;
            *(bf16_t*)(smem + 32768 + d * 512 + ((s * 2) ^ ((d & 7) << 4))) = vv[j];
        }
    }

    bf16x8 qf[4][2];
    #pragma unroll
    for (int mi = 0; mi < 4; ++mi) {
        int row = mi * 64 + w * 16 + l15;
        #pragma unroll
        for (int kk = 0; kk < 2; ++kk)
            qf[mi][kk] = *(const bf16x8*)(qg + base + (long)row * HD + kk * 32 + l4 * 8);
    }

    __syncthreads();

    f32x4 oacc[4][4];
    float mrow[4][4], lrow[4][4];
    #pragma unroll
    for (int mi = 0; mi < 4; ++mi) {
        #pragma unroll
        for (int di = 0; di < 4; ++di) oacc[mi][di] = f32x4{0.f, 0.f, 0.f, 0.f};
        #pragma unroll
        for (int r = 0; r < 4; ++r) { mrow[mi][r] = -1e30f; lrow[mi][r] = 0.f; }
    }

    char* Pw = smem + 65536 + w * 4096;
    const int ntiles = (w < 2) ? 7 : 8;
    const float LOG2E = 1.44269504089f;

    for (int st = 0; st < ntiles; ++st) {
        f32x4 sacc[4][2];
        #pragma unroll
        for (int mi = 0; mi < 4; ++mi)
            #pragma unroll
            for (int ni = 0; ni < 2; ++ni) sacc[mi][ni] = f32x4{0.f, 0.f, 0.f, 0.f};

        #pragma unroll
        for (int kk = 0; kk < 2; ++kk) {
            #pragma unroll
            for (int ni = 0; ni < 2; ++ni) {
                int s = st * 32 + ni * 16 + l15;
                bf16x8 kf = *(const bf16x8*)(smem + s * 128 + (((kk * 32 + l4 * 8) * 2) ^ ((s & 7) << 4)));
                #pragma unroll
                for (int mi = 0; mi < 4; ++mi) {
                    if (st * 32 <= mi * 64 + w * 16 + 15)
                        sacc[mi][ni] = __builtin_amdgcn_mfma_f32_16x16x32_bf16(qf[mi][kk], kf, sacc[mi][ni], 0, 0, 0);
                }
            }
        }

        #pragma unroll
        for (int mi = 0; mi < 4; ++mi) {
            const int R = mi * 64 + w * 16;
            if (st * 32 > R + 15) continue;
            const bool needmask = (st * 32 + 31 > R);
            #pragma unroll
            for (int r = 0; r < 4; ++r) {
                float s0 = sacc[mi][0][r] * 0.125f;
                float s1 = sacc[mi][1][r] * 0.125f;
                if (needmask) {
                    int row = R + l4 * 4 + r;
                    if (st * 32 + l15 > row)      s0 = -1e30f;
                    if (st * 32 + 16 + l15 > row) s1 = -1e30f;
                }
                float mx = fmaxf(s0, s1);
                mx = fmaxf(mx, __shfl_xor(mx, 1));
                mx = fmaxf(mx, __shfl_xor(mx, 2));
                mx = fmaxf(mx, __shfl_xor(mx, 4));
                mx = fmaxf(mx, __shfl_xor(mx, 8));
                float mold = mrow[mi][r];
                float mnew = fmaxf(mold, mx);
                float alpha = exp2f((mold - mnew) * LOG2E);
                float p0 = exp2f((s0 - mnew) * LOG2E);
                float p1 = exp2f((s1 - mnew) * LOG2E);
                mrow[mi][r] = mnew;
                float rs = p0 + p1;
                rs += __shfl_xor(rs, 1);
                rs += __shfl_xor(rs, 2);
                rs += __shfl_xor(rs, 4);
                rs += __shfl_xor(rs, 8);
                lrow[mi][r] = lrow[mi][r] * alpha + rs;
                #pragma unroll
                for (int di = 0; di < 4; ++di) oacc[mi][di][r] *= alpha;
                int q = mi * 16 + l4 * 4 + r;
                *(bf16_t*)(Pw + q * 64 + ((l15 * 2) ^ ((q & 3) << 4))) = (bf16_t)p0;
                *(bf16_t*)(Pw + q * 64 + ((32 + l15 * 2) ^ ((q & 3) << 4))) = (bf16_t)p1;
            }
        }

        #pragma unroll
        for (int mi = 0; mi < 4; ++mi) {
            if (st * 32 > mi * 64 + w * 16 + 15) continue;
            int q = mi * 16 + l15;
            bf16x8 pf = *(const bf16x8*)(Pw + q * 64 + ((l4 * 16) ^ ((q & 3) << 4)));
            #pragma unroll
            for (int di = 0; di < 4; ++di) {
                int d = di * 16 + l15;
                bf16x8 vf = *(const bf16x8*)(smem + 32768 + d * 512 + (((st * 32 + l4 * 8) * 2) ^ ((d & 7) << 4)));
                oacc[mi][di] = __builtin_amdgcn_mfma_f32_16x16x32_bf16(pf, vf, oacc[mi][di], 0, 0, 0);
            }
        }
    }

    #pragma unroll
    for (int mi = 0; mi < 4; ++mi) {
        #pragma unroll
        for (int r = 0; r < 4; ++r) {
            float inv = 1.f / lrow[mi][r];
            long row = mi * 64 + w * 16 + l4 * 4 + r;
            #pragma unroll
            for (int di = 0; di < 4; ++di)
                out[base + row * HD + di * 16 + l15] = oacc[mi][di][r] * inv;
        }
    }
}

extern "C" void kernel_launch(void* const* d_in, const int* in_sizes, int n_in,
                              void* d_out, int out_size, void* d_ws, size_t ws_size,
                              hipStream_t stream) {
    const float* x  = (const float*)d_in[0];
    const float* Wq = (const float*)d_in[1];
    const float* Wk = (const float*)d_in[2];
    const float* Wv = (const float*)d_in[3];
    float* out = (float*)d_out;

    bf16_t* Wf = (bf16_t*)d_ws;                       // 147,456 B fragment-major W
    bf16_t* qg = (bf16_t*)((char*)d_ws + (1 << 20));
    bf16_t* kg = qg + (long)MROWS * HD;
    bf16_t* vg = kg + (long)MROWS * HD;

    wconv_kernel<<<dim3(288), dim3(256), 0, stream>>>(Wq, Wk, Wv, Wf);
    qkv_kernel<<<dim3(256), dim3(512), 0, stream>>>(x, Wf, qg, kg, vg);
    attn_kernel<<<dim3(BATCH), dim3(256), 0, stream>>>(qg, kg, vg, out);
}

// Round 5
// 152.180 us; speedup vs baseline: 3.1988x; 2.2698x over previous
//
#include <hip/hip_runtime.h>

#define BATCH 512
#define SEQ   256
#define CEMB  384
#define HD    64
#define MROWS (BATCH*SEQ)

typedef __bf16 bf16_t;
typedef __bf16 bf16x4 __attribute__((ext_vector_type(4)));
typedef __bf16 bf16x8 __attribute__((ext_vector_type(8)));
typedef float  f32x4  __attribute__((ext_vector_type(4)));

// ---------- kernel 1: gather W into MFMA-fragment-major bf16 array Wf ----------
// Wf element idx = (f*64 + lane)*8 + j ; f = s*12 + ni (s=K-step 0..11, ni=N-tile 0..11)
// value = W_m[k][d] with n = ni*16 + (lane&15), k = s*32 + (lane>>4)*8 + j, m = n/64, d = n%64
__global__ void wconv_kernel(const float* __restrict__ Wq, const float* __restrict__ Wk,
                             const float* __restrict__ Wv, bf16_t* __restrict__ Wf) {
    int idx = blockIdx.x * 256 + threadIdx.x;
    if (idx >= 144 * 512) return;
    int j = idx & 7, lane = (idx >> 3) & 63, f = idx >> 9;
    int ni = f % 12, s = f / 12;
    int n = ni * 16 + (lane & 15);
    int k = s * 32 + ((lane >> 4) << 3) + j;
    const float* W = (n < 64) ? Wq : ((n < 128) ? Wk : Wv);
    Wf[idx] = (bf16_t)W[k * HD + (n & 63)];
}

// ---------- kernel 2: qkv projection — no LDS, no barriers, B from L2 ----------
// 4096 independent waves; each owns a 32-row unit (two 16-row MFMA row-fragments
// sharing every B-fragment). B-fragment addresses identical across all waves -> L2-resident.
// __launch_bounds__(256,2): 256-VGPR budget, live ~150 -> no spill possible.
__global__ __launch_bounds__(256, 2)
void qkv_kernel(const float* __restrict__ x, const bf16_t* __restrict__ Wf,
                bf16_t* __restrict__ qg, bf16_t* __restrict__ kg, bf16_t* __restrict__ vg) {
    const int tid = threadIdx.x;
    const int lane = tid & 63;
    const int l15 = lane & 15, l4 = lane >> 4;
    const int wid = blockIdx.x * 4 + (tid >> 6);      // 0..4095
    const long rowbase = (long)wid * 32;

    const float* aptr0 = x + (rowbase + l15) * CEMB + l4 * 8;        // rows 0-15 of unit
    const float* aptr1 = aptr0 + 16 * CEMB;                          // rows 16-31
    const char* wp = (const char*)Wf + lane * 16;

    f32x4 acc[2][12];
    #pragma unroll
    for (int h = 0; h < 2; ++h)
        #pragma unroll
        for (int ni = 0; ni < 12; ++ni) acc[h][ni] = f32x4{0.f, 0.f, 0.f, 0.f};

    #pragma unroll
    for (int ks = 0; ks < 12; ++ks) {
        float4 r0a = *(const float4*)(aptr0 + ks * 32);
        float4 r0b = *(const float4*)(aptr0 + ks * 32 + 4);
        float4 r1a = *(const float4*)(aptr1 + ks * 32);
        float4 r1b = *(const float4*)(aptr1 + ks * 32 + 4);
        bf16x8 af0, af1;
        af0[0] = (bf16_t)r0a.x; af0[1] = (bf16_t)r0a.y; af0[2] = (bf16_t)r0a.z; af0[3] = (bf16_t)r0a.w;
        af0[4] = (bf16_t)r0b.x; af0[5] = (bf16_t)r0b.y; af0[6] = (bf16_t)r0b.z; af0[7] = (bf16_t)r0b.w;
        af1[0] = (bf16_t)r1a.x; af1[1] = (bf16_t)r1a.y; af1[2] = (bf16_t)r1a.z; af1[3] = (bf16_t)r1a.w;
        af1[4] = (bf16_t)r1b.x; af1[5] = (bf16_t)r1b.y; af1[6] = (bf16_t)r1b.z; af1[7] = (bf16_t)r1b.w;
        #pragma unroll
        for (int ni = 0; ni < 12; ++ni) {
            bf16x8 bf = *(const bf16x8*)(wp + (ks * 12 + ni) * 1024);
            acc[0][ni] = __builtin_amdgcn_mfma_f32_16x16x32_bf16(af0, bf, acc[0][ni], 0, 0, 0);
            acc[1][ni] = __builtin_amdgcn_mfma_f32_16x16x32_bf16(af1, bf, acc[1][ni], 0, 0, 0);
        }
    }

    #pragma unroll
    for (int h = 0; h < 2; ++h) {
        #pragma unroll
        for (int ni = 0; ni < 12; ++ni) {
            int col = ni * 16 + l15;
            bf16_t* dst = (col < 64) ? qg : ((col < 128) ? kg : vg);
            int d = col & 63;
            #pragma unroll
            for (int r = 0; r < 4; ++r) {
                long rg = rowbase + h * 16 + l4 * 4 + r;
                dst[rg * HD + d] = (bf16_t)acc[h][ni][r];
            }
        }
    }
}

// ---------- kernel 3: causal flash attention, one block per batch (unchanged) ----------
__global__ __launch_bounds__(256, 2)
void attn_kernel(const bf16_t* __restrict__ qg, const bf16_t* __restrict__ kg,
                 const bf16_t* __restrict__ vg, float* __restrict__ out) {
    __shared__ char smem[81920];
    // [0,32768):     K  [256][64] bf16, swizzle ^((s&7)<<4)
    // [32768,65536): Vt [64][256] bf16, swizzle ^((d&7)<<4)
    // [65536,81920): P  per-wave [64][32] bf16, swizzle ^((q&3)<<4)

    const int tid = threadIdx.x;
    const int w = tid >> 6, lane = tid & 63;
    const int l15 = lane & 15, l4 = lane >> 4;
    const long base = (long)blockIdx.x * SEQ * HD;

    for (int it = 0; it < 8; ++it) {
        int i = tid + it * 256;
        int s = i >> 3, cb = (i & 7) * 16;
        bf16x8 kv = *(const bf16x8*)(kg + base + (long)i * 8);
        *(bf16x8*)(smem + s * 128 + (cb ^ ((s & 7) << 4))) = kv;
    }
    for (int it = 0; it < 8; ++it) {
        int i = tid + it * 256;
        int s = i >> 3, d0 = (i & 7) * 8;
        bf16x8 vv = *(const bf16x8*)(vg + base + (long)i * 8);
        #pragma unroll
        for (int j = 0; j < 8; ++j) {
            int d = d0 + j;
            *(bf16_t*)(smem + 32768 + d * 512 + ((s * 2) ^ ((d & 7) << 4))) = vv[j];
        }
    }

    bf16x8 qf[4][2];
    #pragma unroll
    for (int mi = 0; mi < 4; ++mi) {
        int row = mi * 64 + w * 16 + l15;
        #pragma unroll
        for (int kk = 0; kk < 2; ++kk)
            qf[mi][kk] = *(const bf16x8*)(qg + base + (long)row * HD + kk * 32 + l4 * 8);
    }

    __syncthreads();

    f32x4 oacc[4][4];
    float mrow[4][4], lrow[4][4];
    #pragma unroll
    for (int mi = 0; mi < 4; ++mi) {
        #pragma unroll
        for (int di = 0; di < 4; ++di) oacc[mi][di] = f32x4{0.f, 0.f, 0.f, 0.f};
        #pragma unroll
        for (int r = 0; r < 4; ++r) { mrow[mi][r] = -1e30f; lrow[mi][r] = 0.f; }
    }

    char* Pw = smem + 65536 + w * 4096;
    const int ntiles = (w < 2) ? 7 : 8;
    const float LOG2E = 1.44269504089f;

    for (int st = 0; st < ntiles; ++st) {
        f32x4 sacc[4][2];
        #pragma unroll
        for (int mi = 0; mi < 4; ++mi)
            #pragma unroll
            for (int ni = 0; ni < 2; ++ni) sacc[mi][ni] = f32x4{0.f, 0.f, 0.f, 0.f};

        #pragma unroll
        for (int kk = 0; kk < 2; ++kk) {
            #pragma unroll
            for (int ni = 0; ni < 2; ++ni) {
                int s = st * 32 + ni * 16 + l15;
                bf16x8 kf = *(const bf16x8*)(smem + s * 128 + (((kk * 32 + l4 * 8) * 2) ^ ((s & 7) << 4)));
                #pragma unroll
                for (int mi = 0; mi < 4; ++mi) {
                    if (st * 32 <= mi * 64 + w * 16 + 15)
                        sacc[mi][ni] = __builtin_amdgcn_mfma_f32_16x16x32_bf16(qf[mi][kk], kf, sacc[mi][ni], 0, 0, 0);
                }
            }
        }

        #pragma unroll
        for (int mi = 0; mi < 4; ++mi) {
            const int R = mi * 64 + w * 16;
            if (st * 32 > R + 15) continue;
            const bool needmask = (st * 32 + 31 > R);
            #pragma unroll
            for (int r = 0; r < 4; ++r) {
                float s0 = sacc[mi][0][r] * 0.125f;
                float s1 = sacc[mi][1][r] * 0.125f;
                if (needmask) {
                    int row = R + l4 * 4 + r;
                    if (st * 32 + l15 > row)      s0 = -1e30f;
                    if (st * 32 + 16 + l15 > row) s1 = -1e30f;
                }
                float mx = fmaxf(s0, s1);
                mx = fmaxf(mx, __shfl_xor(mx, 1));
                mx = fmaxf(mx, __shfl_xor(mx, 2));
                mx = fmaxf(mx, __shfl_xor(mx, 4));
                mx = fmaxf(mx, __shfl_xor(mx, 8));
                float mold = mrow[mi][r];
                float mnew = fmaxf(mold, mx);
                float alpha = exp2f((mold - mnew) * LOG2E);
                float p0 = exp2f((s0 - mnew) * LOG2E);
                float p1 = exp2f((s1 - mnew) * LOG2E);
                mrow[mi][r] = mnew;
                float rs = p0 + p1;
                rs += __shfl_xor(rs, 1);
                rs += __shfl_xor(rs, 2);
                rs += __shfl_xor(rs, 4);
                rs += __shfl_xor(rs, 8);
                lrow[mi][r] = lrow[mi][r] * alpha + rs;
                #pragma unroll
                for (int di = 0; di < 4; ++di) oacc[mi][di][r] *= alpha;
                int q = mi * 16 + l4 * 4 + r;
                *(bf16_t*)(Pw + q * 64 + ((l15 * 2) ^ ((q & 3) << 4))) = (bf16_t)p0;
                *(bf16_t*)(Pw + q * 64 + ((32 + l15 * 2) ^ ((q & 3) << 4))) = (bf16_t)p1;
            }
        }

        #pragma unroll
        for (int mi = 0; mi < 4; ++mi) {
            if (st * 32 > mi * 64 + w * 16 + 15) continue;
            int q = mi * 16 + l15;
            bf16x8 pf = *(const bf16x8*)(Pw + q * 64 + ((l4 * 16) ^ ((q & 3) << 4)));
            #pragma unroll
            for (int di = 0; di < 4; ++di) {
                int d = di * 16 + l15;
                bf16x8 vf = *(const bf16x8*)(smem + 32768 + d * 512 + (((st * 32 + l4 * 8) * 2) ^ ((d & 7) << 4)));
                oacc[mi][di] = __builtin_amdgcn_mfma_f32_16x16x32_bf16(pf, vf, oacc[mi][di], 0, 0, 0);
            }
        }
    }

    #pragma unroll
    for (int mi = 0; mi < 4; ++mi) {
        #pragma unroll
        for (int r = 0; r < 4; ++r) {
            float inv = 1.f / lrow[mi][r];
            long row = mi * 64 + w * 16 + l4 * 4 + r;
            #pragma unroll
            for (int di = 0; di < 4; ++di)
                out[base + row * HD + di * 16 + l15] = oacc[mi][di][r] * inv;
        }
    }
}

extern "C" void kernel_launch(void* const* d_in, const int* in_sizes, int n_in,
                              void* d_out, int out_size, void* d_ws, size_t ws_size,
                              hipStream_t stream) {
    const float* x  = (const float*)d_in[0];
    const float* Wq = (const float*)d_in[1];
    const float* Wk = (const float*)d_in[2];
    const float* Wv = (const float*)d_in[3];
    float* out = (float*)d_out;

    bf16_t* Wf = (bf16_t*)d_ws;                       // 147,456 B fragment-major W
    bf16_t* qg = (bf16_t*)((char*)d_ws + (1 << 20));
    bf16_t* kg = qg + (long)MROWS * HD;
    bf16_t* vg = kg + (long)MROWS * HD;

    wconv_kernel<<<dim3(288), dim3(256), 0, stream>>>(Wq, Wk, Wv, Wf);
    qkv_kernel<<<dim3(MROWS / 32 / 4), dim3(256), 0, stream>>>(x, Wf, qg, kg, vg);
    attn_kernel<<<dim3(BATCH), dim3(256), 0, stream>>>(qg, kg, vg, out);
}

// Round 6
// 146.741 us; speedup vs baseline: 3.3174x; 1.0371x over previous
//
#include <hip/hip_runtime.h>

#define BATCH 512
#define SEQ   256
#define CEMB  384
#define HD    64
#define MROWS (BATCH*SEQ)

typedef __bf16 bf16_t;
typedef __bf16 bf16x4 __attribute__((ext_vector_type(4)));
typedef __bf16 bf16x8 __attribute__((ext_vector_type(8)));
typedef float  f32x4  __attribute__((ext_vector_type(4)));

// ---------- kernel 1: gather W into MFMA-fragment-major bf16 array Wf ----------
// Wf element idx = (f*64 + lane)*8 + j ; f = s*12 + ni (s=K-step 0..11, ni=N-tile 0..11)
// value = W_m[k][d] with n = ni*16 + (lane&15), k = s*32 + (lane>>4)*8 + j, m = n/64, d = n%64
__global__ void wconv_kernel(const float* __restrict__ Wq, const float* __restrict__ Wk,
                             const float* __restrict__ Wv, bf16_t* __restrict__ Wf) {
    int idx = blockIdx.x * 256 + threadIdx.x;
    if (idx >= 144 * 512) return;
    int j = idx & 7, lane = (idx >> 3) & 63, f = idx >> 9;
    int ni = f % 12, s = f / 12;
    int n = ni * 16 + (lane & 15);
    int k = s * 32 + ((lane >> 4) << 3) + j;
    const float* W = (n < 64) ? Wq : ((n < 128) ? Wk : Wv);
    Wf[idx] = (bf16_t)W[k * HD + (n & 63)];
}

__device__ inline bf16x8 cvt8(float4 a, float4 b) {
    bf16x8 r;
    r[0] = (bf16_t)a.x; r[1] = (bf16_t)a.y; r[2] = (bf16_t)a.z; r[3] = (bf16_t)a.w;
    r[4] = (bf16_t)b.x; r[5] = (bf16_t)b.y; r[6] = (bf16_t)b.z; r[7] = (bf16_t)b.w;
    return r;
}

// ---------- kernel 2: qkv projection — no LDS, software-pipelined, B from L2 ----------
// 4096 independent waves; each owns a 32-row unit (two 16-row A-fragments sharing each
// B-fragment). Explicit 1-step double-buffered pipeline: B/A loads for step ks+1 are
// batch-issued BEFORE the MFMAs of step ks, so ~16 loads stay in flight per wave.
__global__ __launch_bounds__(256, 2)
void qkv_kernel(const float* __restrict__ x, const bf16_t* __restrict__ Wf,
                bf16_t* __restrict__ qg, bf16_t* __restrict__ kg, bf16_t* __restrict__ vg) {
    const int tid = threadIdx.x;
    const int lane = tid & 63;
    const int l15 = lane & 15, l4 = lane >> 4;
    const int wid = blockIdx.x * 4 + (tid >> 6);      // 0..4095
    const long rowbase = (long)wid * 32;

    const float* aptr0 = x + (rowbase + l15) * CEMB + l4 * 8;        // rows 0-15
    const float* aptr1 = aptr0 + 16 * CEMB;                          // rows 16-31
    const char* wp = (const char*)Wf + lane * 16;

    f32x4 acc[2][12];
    #pragma unroll
    for (int h = 0; h < 2; ++h)
        #pragma unroll
        for (int ni = 0; ni < 12; ++ni) acc[h][ni] = f32x4{0.f, 0.f, 0.f, 0.f};

    bf16x8 B0[12], B1[12];
    float4 A0[4], A1[4];

    // prologue: stage ks=0
    #pragma unroll
    for (int ni = 0; ni < 12; ++ni) B0[ni] = *(const bf16x8*)(wp + ni * 1024);
    A0[0] = *(const float4*)(aptr0);
    A0[1] = *(const float4*)(aptr0 + 4);
    A0[2] = *(const float4*)(aptr1);
    A0[3] = *(const float4*)(aptr1 + 4);

#define QKV_STEP(KS, BC, BN, AC, AN)                                                      \
    {                                                                                     \
        if ((KS) < 11) {                                                                  \
            _Pragma("unroll")                                                             \
            for (int ni = 0; ni < 12; ++ni)                                               \
                BN[ni] = *(const bf16x8*)(wp + (((KS) + 1) * 12 + ni) * 1024);            \
            AN[0] = *(const float4*)(aptr0 + ((KS) + 1) * 32);                            \
            AN[1] = *(const float4*)(aptr0 + ((KS) + 1) * 32 + 4);                        \
            AN[2] = *(const float4*)(aptr1 + ((KS) + 1) * 32);                            \
            AN[3] = *(const float4*)(aptr1 + ((KS) + 1) * 32 + 4);                        \
        }                                                                                 \
        bf16x8 af0 = cvt8(AC[0], AC[1]);                                                  \
        bf16x8 af1 = cvt8(AC[2], AC[3]);                                                  \
        _Pragma("unroll")                                                                 \
        for (int ni = 0; ni < 12; ++ni) {                                                 \
            acc[0][ni] = __builtin_amdgcn_mfma_f32_16x16x32_bf16(af0, BC[ni], acc[0][ni], 0, 0, 0); \
            acc[1][ni] = __builtin_amdgcn_mfma_f32_16x16x32_bf16(af1, BC[ni], acc[1][ni], 0, 0, 0); \
        }                                                                                 \
    }

    QKV_STEP(0,  B0, B1, A0, A1)
    QKV_STEP(1,  B1, B0, A1, A0)
    QKV_STEP(2,  B0, B1, A0, A1)
    QKV_STEP(3,  B1, B0, A1, A0)
    QKV_STEP(4,  B0, B1, A0, A1)
    QKV_STEP(5,  B1, B0, A1, A0)
    QKV_STEP(6,  B0, B1, A0, A1)
    QKV_STEP(7,  B1, B0, A1, A0)
    QKV_STEP(8,  B0, B1, A0, A1)
    QKV_STEP(9,  B1, B0, A1, A0)
    QKV_STEP(10, B0, B1, A0, A1)
    QKV_STEP(11, B1, B0, A1, A0)
#undef QKV_STEP

    #pragma unroll
    for (int h = 0; h < 2; ++h) {
        #pragma unroll
        for (int ni = 0; ni < 12; ++ni) {
            int col = ni * 16 + l15;
            bf16_t* dst = (col < 64) ? qg : ((col < 128) ? kg : vg);
            int d = col & 63;
            #pragma unroll
            for (int r = 0; r < 4; ++r) {
                long rg = rowbase + h * 16 + l4 * 4 + r;
                dst[rg * HD + d] = (bf16_t)acc[h][ni][r];
            }
        }
    }
}

// ---------- kernel 3: causal flash attention, one block per batch (unchanged) ----------
__global__ __launch_bounds__(256, 2)
void attn_kernel(const bf16_t* __restrict__ qg, const bf16_t* __restrict__ kg,
                 const bf16_t* __restrict__ vg, float* __restrict__ out) {
    __shared__ char smem[81920];
    // [0,32768):     K  [256][64] bf16, swizzle ^((s&7)<<4)
    // [32768,65536): Vt [64][256] bf16, swizzle ^((d&7)<<4)
    // [65536,81920): P  per-wave [64][32] bf16, swizzle ^((q&3)<<4)

    const int tid = threadIdx.x;
    const int w = tid >> 6, lane = tid & 63;
    const int l15 = lane & 15, l4 = lane >> 4;
    const long base = (long)blockIdx.x * SEQ * HD;

    for (int it = 0; it < 8; ++it) {
        int i = tid + it * 256;
        int s = i >> 3, cb = (i & 7) * 16;
        bf16x8 kv = *(const bf16x8*)(kg + base + (long)i * 8);
        *(bf16x8*)(smem + s * 128 + (cb ^ ((s & 7) << 4))) = kv;
    }
    for (int it = 0; it < 8; ++it) {
        int i = tid + it * 256;
        int s = i >> 3, d0 = (i & 7) * 8;
        bf16x8 vv = *(const bf16x8*)(vg + base + (long)i * 8);
        #pragma unroll
        for (int j = 0; j < 8; ++j) {
            int d = d0 + j;
            *(bf16_t*)(smem + 32768 + d * 512 + ((s * 2) ^ ((d & 7) << 4))) = vv[j];
        }
    }

    bf16x8 qf[4][2];
    #pragma unroll
    for (int mi = 0; mi < 4; ++mi) {
        int row = mi * 64 + w * 16 + l15;
        #pragma unroll
        for (int kk = 0; kk < 2; ++kk)
            qf[mi][kk] = *(const bf16x8*)(qg + base + (long)row * HD + kk * 32 + l4 * 8);
    }

    __syncthreads();

    f32x4 oacc[4][4];
    float mrow[4][4], lrow[4][4];
    #pragma unroll
    for (int mi = 0; mi < 4; ++mi) {
        #pragma unroll
        for (int di = 0; di < 4; ++di) oacc[mi][di] = f32x4{0.f, 0.f, 0.f, 0.f};
        #pragma unroll
        for (int r = 0; r < 4; ++r) { mrow[mi][r] = -1e30f; lrow[mi][r] = 0.f; }
    }

    char* Pw = smem + 65536 + w * 4096;
    const int ntiles = (w < 2) ? 7 : 8;
    const float LOG2E = 1.44269504089f;

    for (int st = 0; st < ntiles; ++st) {
        f32x4 sacc[4][2];
        #pragma unroll
        for (int mi = 0; mi < 4; ++mi)
            #pragma unroll
            for (int ni = 0; ni < 2; ++ni) sacc[mi][ni] = f32x4{0.f, 0.f, 0.f, 0.f};

        #pragma unroll
        for (int kk = 0; kk < 2; ++kk) {
            #pragma unroll
            for (int ni = 0; ni < 2; ++ni) {
                int s = st * 32 + ni * 16 + l15;
                bf16x8 kf = *(const bf16x8*)(smem + s * 128 + (((kk * 32 + l4 * 8) * 2) ^ ((s & 7) << 4)));
                #pragma unroll
                for (int mi = 0; mi < 4; ++mi) {
                    if (st * 32 <= mi * 64 + w * 16 + 15)
                        sacc[mi][ni] = __builtin_amdgcn_mfma_f32_16x16x32_bf16(qf[mi][kk], kf, sacc[mi][ni], 0, 0, 0);
                }
            }
        }

        #pragma unroll
        for (int mi = 0; mi < 4; ++mi) {
            const int R = mi * 64 + w * 16;
            if (st * 32 > R + 15) continue;
            const bool needmask = (st * 32 + 31 > R);
            #pragma unroll
            for (int r = 0; r < 4; ++r) {
                float s0 = sacc[mi][0][r] * 0.125f;
                float s1 = sacc[mi][1][r] * 0.125f;
                if (needmask) {
                    int row = R + l4 * 4 + r;
                    if (st * 32 + l15 > row)      s0 = -1e30f;
                    if (st * 32 + 16 + l15 > row) s1 = -1e30f;
                }
                float mx = fmaxf(s0, s1);
                mx = fmaxf(mx, __shfl_xor(mx, 1));
                mx = fmaxf(mx, __shfl_xor(mx, 2));
                mx = fmaxf(mx, __shfl_xor(mx, 4));
                mx = fmaxf(mx, __shfl_xor(mx, 8));
                float mold = mrow[mi][r];
                float mnew = fmaxf(mold, mx);
                float alpha = exp2f((mold - mnew) * LOG2E);
                float p0 = exp2f((s0 - mnew) * LOG2E);
                float p1 = exp2f((s1 - mnew) * LOG2E);
                mrow[mi][r] = mnew;
                float rs = p0 + p1;
                rs += __shfl_xor(rs, 1);
                rs += __shfl_xor(rs, 2);
                rs += __shfl_xor(rs, 4);
                rs += __shfl_xor(rs, 8);
                lrow[mi][r] = lrow[mi][r] * alpha + rs;
                #pragma unroll
                for (int di = 0; di < 4; ++di) oacc[mi][di][r] *= alpha;
                int q = mi * 16 + l4 * 4 + r;
                *(bf16_t*)(Pw + q * 64 + ((l15 * 2) ^ ((q & 3) << 4))) = (bf16_t)p0;
                *(bf16_t*)(Pw + q * 64 + ((32 + l15 * 2) ^ ((q & 3) << 4))) = (bf16_t)p1;
            }
        }

        #pragma unroll
        for (int mi = 0; mi < 4; ++mi) {
            if (st * 32 > mi * 64 + w * 16 + 15) continue;
            int q = mi * 16 + l15;
            bf16x8 pf = *(const bf16x8*)(Pw + q * 64 + ((l4 * 16) ^ ((q & 3) << 4)));
            #pragma unroll
            for (int di = 0; di < 4; ++di) {
                int d = di * 16 + l15;
                bf16x8 vf = *(const bf16x8*)(smem + 32768 + d * 512 + (((st * 32 + l4 * 8) * 2) ^ ((d & 7) << 4)));
                oacc[mi][di] = __builtin_amdgcn_mfma_f32_16x16x32_bf16(pf, vf, oacc[mi][di], 0, 0, 0);
            }
        }
    }

    #pragma unroll
    for (int mi = 0; mi < 4; ++mi) {
        #pragma unroll
        for (int r = 0; r < 4; ++r) {
            float inv = 1.f / lrow[mi][r];
            long row = mi * 64 + w * 16 + l4 * 4 + r;
            #pragma unroll
            for (int di = 0; di < 4; ++di)
                out[base + row * HD + di * 16 + l15] = oacc[mi][di][r] * inv;
        }
    }
}

extern "C" void kernel_launch(void* const* d_in, const int* in_sizes, int n_in,
                              void* d_out, int out_size, void* d_ws, size_t ws_size,
                              hipStream_t stream) {
    const float* x  = (const float*)d_in[0];
    const float* Wq = (const float*)d_in[1];
    const float* Wk = (const float*)d_in[2];
    const float* Wv = (const float*)d_in[3];
    float* out = (float*)d_out;

    bf16_t* Wf = (bf16_t*)d_ws;                       // 147,456 B fragment-major W
    bf16_t* qg = (bf16_t*)((char*)d_ws + (1 << 20));
    bf16_t* kg = qg + (long)MROWS * HD;
    bf16_t* vg = kg + (long)MROWS * HD;

    wconv_kernel<<<dim3(288), dim3(256), 0, stream>>>(Wq, Wk, Wv, Wf);
    qkv_kernel<<<dim3(MROWS / 32 / 4), dim3(256), 0, stream>>>(x, Wf, qg, kg, vg);
    attn_kernel<<<dim3(BATCH), dim3(256), 0, stream>>>(qg, kg, vg, out);
}